// Round 10
// baseline (364.376 us; speedup 1.0000x reference)
//
#include <hip/hip_runtime.h>
#include <stdint.h>

#define B_ 128
#define T_ 1000
#define H_ 512
#define HH 256        // per-wave half of H
#define K_ 10         // DMA prefetch depth = steps per phase
#define NPH 100       // T_/K_

typedef float vfloat4 __attribute__((ext_vector_type(4)));

// Counted vmcnt wait (literal N).
#define WAITV(n) asm volatile("s_waitcnt vmcnt(" #n ")" ::: "memory")

// DPP-based add of a lane-shifted copy. row_shr:N = 0x110|N, row_bcast:15/31 = 0x142/0x143.
template <int CTRL>
__device__ __forceinline__ float dpp_add(float x) {
    int moved = __builtin_amdgcn_update_dpp(0, __float_as_int(x), CTRL, 0xf, 0xf, true);
    return x + __int_as_float(moved);
}

// Wave64 sum of 3 values (3-way ILP covers DPP latency). Totals valid in lane 63.
__device__ __forceinline__ void wave_reduce3(float& p0, float& p1, float& p2) {
    p0 = dpp_add<0x111>(p0); p1 = dpp_add<0x111>(p1); p2 = dpp_add<0x111>(p2);
    p0 = dpp_add<0x112>(p0); p1 = dpp_add<0x112>(p1); p2 = dpp_add<0x112>(p2);
    p0 = dpp_add<0x114>(p0); p1 = dpp_add<0x114>(p1); p2 = dpp_add<0x114>(p2);
    p0 = dpp_add<0x118>(p0); p1 = dpp_add<0x118>(p1); p2 = dpp_add<0x118>(p2);
    p0 = dpp_add<0x142>(p0); p1 = dpp_add<0x142>(p1); p2 = dpp_add<0x142>(p2);
    p0 = dpp_add<0x143>(p0); p1 = dpp_add<0x143>(p1); p2 = dpp_add<0x143>(p2);
}

__device__ __forceinline__ float wave_reduce1(float p) {
    p = dpp_add<0x111>(p); p = dpp_add<0x112>(p); p = dpp_add<0x114>(p);
    p = dpp_add<0x118>(p); p = dpp_add<0x142>(p); p = dpp_add<0x143>(p);
    return p;
}

// tanh(x) = 1 - 2/(e^{2x}+1) via hardware exp2 + rcp.
__device__ __forceinline__ float fast_tanh(float x) {
    float E = __builtin_amdgcn_exp2f(x * 2.885390081777927f);
    float r = __builtin_amdgcn_rcpf(E + 1.0f);
    return __builtin_fmaf(-2.0f, r, 1.0f);
}

// Async global->LDS DMA, 16B/lane. Global src per-lane, LDS dest wave-uniform base.
__device__ __forceinline__ void gl_lds16(const float* g, float* l) {
    __builtin_amdgcn_global_load_lds(
        (const __attribute__((address_space(1))) uint32_t*)g,
        (__attribute__((address_space(3))) uint32_t*)l, 16, 0, 0);
}

__global__ __launch_bounds__(128, 1) void lowrank_rnn_kernel(
    const float* __restrict__ input,   // (B,T,3)
    const float* __restrict__ noise,   // (B,T,H)
    const float* __restrict__ wi,      // (3,H)
    const float* __restrict__ si,      // (3,)
    const float* __restrict__ m,       // (H,2)
    const float* __restrict__ n,       // (H,2)
    const float* __restrict__ wo,      // (H,1)
    const float* __restrict__ so,      // (1,)
    const float* __restrict__ h0,      // (H,)
    float* __restrict__ out)           // [output (B,T,1) | traj (B,T+1,H)]
{
    const int b    = blockIdx.x;       // one batch element per 2-wave block
    const int tid  = threadIdx.x;
    const int wid  = tid >> 6;         // wave 0: units 0..255, wave 1: 256..511
    const int lane = tid & 63;
    const int J    = wid * HH + lane * 4;   // this lane's 4 hidden units

    __shared__ __align__(16) float   zring[2][K_][HH];  // 20 KB noise DMA ring
    __shared__ __align__(16) vfloat4 xch[4][2];         // cross-wave partial slots
    __shared__ float xs[T_ * 3];                        // 12 KB input
    __shared__ float os[T_ + 1];                        //  4 KB outputs

    // Stage x into LDS (VMEM loads older than all DMAs -> retire first).
    {
        const float* xg = input + (size_t)b * T_ * 3;
        for (int i = tid; i < 750; i += 128)
            *(vfloat4*)&xs[i * 4] = *(const vfloat4*)(xg + i * 4);
    }

    // Per-lane constants (ALPHA=0.2 folded into m, wi; so into wo).
    float h[4], n0v[4], n1v[4], m0S[4], m1S[4], wof[4], wS0[4], wS1[4], wS2[4];
    {
        const float so0 = so[0];
        vfloat4 v0 = *(const vfloat4*)(n + 2 * J);
        vfloat4 v1 = *(const vfloat4*)(n + 2 * J + 4);
        n0v[0]=v0.x; n1v[0]=v0.y; n0v[1]=v0.z; n1v[1]=v0.w;
        n0v[2]=v1.x; n1v[2]=v1.y; n0v[3]=v1.z; n1v[3]=v1.w;
        vfloat4 w0 = *(const vfloat4*)(m + 2 * J);
        vfloat4 w1 = *(const vfloat4*)(m + 2 * J + 4);
        m0S[0]=0.2f*w0.x; m1S[0]=0.2f*w0.y; m0S[1]=0.2f*w0.z; m1S[1]=0.2f*w0.w;
        m0S[2]=0.2f*w1.x; m1S[2]=0.2f*w1.y; m0S[3]=0.2f*w1.z; m1S[3]=0.2f*w1.w;
        vfloat4 vw = *(const vfloat4*)(wo + J);
        wof[0]=vw.x*so0; wof[1]=vw.y*so0; wof[2]=vw.z*so0; wof[3]=vw.w*so0;
        #pragma unroll
        for (int i = 0; i < 3; ++i) {
            float s = 0.2f * si[i];
            vfloat4 q = *(const vfloat4*)(wi + i * H_ + J);
            float* dst = (i == 0) ? wS0 : (i == 1) ? wS1 : wS2;
            dst[0]=q.x*s; dst[1]=q.y*s; dst[2]=q.z*s; dst[3]=q.w*s;
        }
        vfloat4 vh = *(const vfloat4*)(h0 + J);
        h[0]=vh.x; h[1]=vh.y; h[2]=vh.z; h[3]=vh.w;
    }

    float* trajBase = out + (size_t)B_ * T_ + (size_t)b * (T_ + 1) * H_;
    {   // trajectories[:,0,:] = h0 (each wave its half)
        vfloat4 v = {h[0], h[1], h[2], h[3]};
        *(vfloat4*)(trajBase + J) = v;
    }

    // DMA prologue: rows 0..K-1 of this wave's z-half.
    const float* gz = noise + (size_t)b * T_ * H_ + J;   // per-lane (16B stride)
    #pragma unroll
    for (int s = 0; s < K_; ++s)
        gl_lds16(gz + (size_t)s * H_, &zring[wid][s][0]);

    const float* gzn    = gz + (size_t)K_ * H_;          // next DMA row
    const float* gzlast = gz + (size_t)(T_ - 1) * H_;
    float*       trp    = trajBase + H_ + J;             // h_1 store position

    // One step. Caller has already executed the counted vmcnt wait.
    auto STEP = [&](int t, int s, const float* gdma,
                    float x0, float x1, float x2) {
        __builtin_amdgcn_sched_barrier(0);
        // z for this step (own half), then re-arm the slot K steps ahead.
        vfloat4 z = *(vfloat4*)((char*)&zring[wid][s][0] + lane * 16);
        gl_lds16(gdma, &zring[wid][s][0]);

        float zz[4] = {z.x, z.y, z.z, z.w};
        float u[4];
        #pragma unroll
        for (int k = 0; k < 4; ++k) {
            float xw = __builtin_fmaf(x0, wS0[k],
                       __builtin_fmaf(x1, wS1[k], x2 * wS2[k]));
            u[k] = __builtin_fmaf(zz[k], 0.05f, xw);
        }

        float r[4];
        #pragma unroll
        for (int k = 0; k < 4; ++k) r[k] = fast_tanh(h[k]);

        float p0 = r[0] * n0v[0], p1 = r[0] * n1v[0], p2 = r[0] * wof[0];
        #pragma unroll
        for (int k = 1; k < 4; ++k) {
            p0 = __builtin_fmaf(r[k], n0v[k], p0);
            p1 = __builtin_fmaf(r[k], n1v[k], p1);
            p2 = __builtin_fmaf(r[k], wof[k], p2);
        }
        wave_reduce3(p0, p1, p2);

        // Cross-wave exchange of half-sums (4-slot ring, barrier-ordered).
        if (lane == 63) {
            vfloat4 v = {p0, p1, p2, 0.f};
            xch[t & 3][wid] = v;
        }
        asm volatile("s_waitcnt lgkmcnt(0)" ::: "memory");
        __builtin_amdgcn_s_barrier();          // raw: vmcnt stays in flight
        __builtin_amdgcn_sched_barrier(0);

        vfloat4 oa = xch[t & 3][0];            // uniform addr -> broadcast read
        vfloat4 ob = xch[t & 3][1];
        float a0 = oa.x + ob.x;                // same order in both waves
        float a1 = oa.y + ob.y;
        if (tid == 0) os[t] = oa.z + ob.z;     // out[t-1] = tanh(h_t)·wo_full

        #pragma unroll
        for (int k = 0; k < 4; ++k) {
            float base = __builtin_fmaf(h[k], 0.8f, u[k]);
            h[k] = __builtin_fmaf(a0, m0S[k], __builtin_fmaf(a1, m1S[k], base));
        }

        // Own-half trajectory store (fire-and-forget; younger than all waited loads).
        vfloat4 hv = {h[0], h[1], h[2], h[3]};
        *(vfloat4*)trp = hv;
        trp += H_;
    };

    // ---- phase 0 (peeled: prologue vmcnt counts 9+s) ----
    {
        float xv[3 * K_];
        #pragma unroll
        for (int i = 0; i < 3 * K_; ++i) xv[i] = xs[i];
        WAITV(9);  STEP(0, 0, gzn, xv[0],  xv[1],  xv[2]);  gzn += H_;
        WAITV(10); STEP(1, 1, gzn, xv[3],  xv[4],  xv[5]);  gzn += H_;
        WAITV(11); STEP(2, 2, gzn, xv[6],  xv[7],  xv[8]);  gzn += H_;
        WAITV(12); STEP(3, 3, gzn, xv[9],  xv[10], xv[11]); gzn += H_;
        WAITV(13); STEP(4, 4, gzn, xv[12], xv[13], xv[14]); gzn += H_;
        WAITV(14); STEP(5, 5, gzn, xv[15], xv[16], xv[17]); gzn += H_;
        WAITV(15); STEP(6, 6, gzn, xv[18], xv[19], xv[20]); gzn += H_;
        WAITV(16); STEP(7, 7, gzn, xv[21], xv[22], xv[23]); gzn += H_;
        WAITV(17); STEP(8, 8, gzn, xv[24], xv[25], xv[26]); gzn += H_;
        WAITV(18); STEP(9, 9, gzn, xv[27], xv[28], xv[29]); gzn += H_;
    }
    // ---- phases 1..98 (steady state: 2 vmem/step -> vmcnt(2K-1)=19) ----
    for (int p = 1; p < NPH - 1; ++p) {
        float xv[3 * K_];
        #pragma unroll
        for (int i = 0; i < 3 * K_; ++i) xv[i] = xs[p * (3 * K_) + i];
        #pragma unroll
        for (int s = 0; s < K_; ++s) {
            WAITV(19);
            STEP(p * K_ + s, s, gzn, xv[3*s], xv[3*s+1], xv[3*s+2]);
            gzn += H_;
        }
    }
    // ---- phase 99 (peeled: DMA clamped to last row) ----
    {
        const int p = NPH - 1;
        float xv[3 * K_];
        #pragma unroll
        for (int i = 0; i < 3 * K_; ++i) xv[i] = xs[p * (3 * K_) + i];
        #pragma unroll
        for (int s = 0; s < K_; ++s) {
            WAITV(19);
            STEP(p * K_ + s, s, gzlast, xv[3*s], xv[3*s+1], xv[3*s+2]);
        }
    }

    // Final output: out[T-1] = tanh(h_T)·wo_full
    {
        float r[4];
        #pragma unroll
        for (int k = 0; k < 4; ++k) r[k] = fast_tanh(h[k]);
        float p2 = r[0] * wof[0];
        #pragma unroll
        for (int k = 1; k < 4; ++k) p2 = __builtin_fmaf(r[k], wof[k], p2);
        p2 = wave_reduce1(p2);
        if (lane == 63) {
            vfloat4 v = {0.f, 0.f, p2, 0.f};
            xch[0][wid] = v;
        }
        asm volatile("s_waitcnt lgkmcnt(0)" ::: "memory");
        __builtin_amdgcn_s_barrier();
        vfloat4 oa = xch[0][0];
        vfloat4 ob = xch[0][1];
        if (tid == 0) os[T_] = oa.z + ob.z;
    }

    __syncthreads();
    float* outp = out + (size_t)b * T_;
    for (int idx = tid; idx < T_; idx += 128)
        outp[idx] = os[idx + 1];
}

extern "C" void kernel_launch(void* const* d_in, const int* in_sizes, int n_in,
                              void* d_out, int out_size, void* d_ws, size_t ws_size,
                              hipStream_t stream) {
    const float* input = (const float*)d_in[0];
    const float* noise = (const float*)d_in[1];
    const float* wi    = (const float*)d_in[2];
    const float* si    = (const float*)d_in[3];
    const float* m     = (const float*)d_in[4];
    const float* n     = (const float*)d_in[5];
    const float* wo    = (const float*)d_in[6];
    const float* so    = (const float*)d_in[7];
    const float* h0    = (const float*)d_in[8];
    float* out = (float*)d_out;

    hipLaunchKernelGGL(lowrank_rnn_kernel, dim3(B_), dim3(128), 0, stream,
                       input, noise, wi, si, m, n, wo, so, h0, out);
}